// Round 5
// baseline (437.868 us; speedup 1.0000x reference)
//
#include <hip/hip_runtime.h>
#include <math.h>

// ---- geometry constants (match reference) ----
#define NA   24
#define NU   128
#define NV   64
#define NW   128   // volume W (x)
#define NH   128   // volume H (y)
#define ND   64    // volume D (z)
#define NS   128   // samples per ray
#define F_STEP 1.5625f            // 2*HS/S = 200/128
#define F_DL  (200.0f / 127.0f)   // linspace(156,356,128) spacing
#define F_L0  156.0f
#define INV_DL (127.0f / 200.0f)

#define NRAYS (NA * NV * NU)      // 196608
#define VOX   (NW * NH * ND)      // 1048576
#define NSEG  4

// padded volume: planes {guard, padz(-1), z0..z63, padz(64), guard} x 130 x 130
#define PPX  130
#define PPY  130
#define PPZ  68
#define PPLANE (PPX * PPY)        // 16900
#define PVN  (PPZ * PPLANE)       // 1,149,200
#define CBASE (2 * PPLANE + PPX + 1)   // voxel(0,0,0) linear offset

typedef float v2f __attribute__((ext_vector_type(2)));
#define AS3 __attribute__((address_space(3)))
#define AS1 __attribute__((address_space(1)))

// cos/sin(k*15 deg)
__device__ __constant__ float CSA[NA] = {
    1.0f,  0.96592582628906829f,  0.86602540378443865f,  0.70710678118654752f,
    0.5f,  0.25881904510252076f,  0.0f,                 -0.25881904510252076f,
   -0.5f, -0.70710678118654752f, -0.86602540378443865f, -0.96592582628906829f,
   -1.0f, -0.96592582628906829f, -0.86602540378443865f, -0.70710678118654752f,
   -0.5f, -0.25881904510252076f,  0.0f,                  0.25881904510252076f,
    0.5f,  0.70710678118654752f,  0.86602540378443865f,  0.96592582628906829f
};
__device__ __constant__ float SNA[NA] = {
    0.0f,  0.25881904510252076f,  0.5f,                  0.70710678118654752f,
    0.86602540378443865f,  0.96592582628906829f,  1.0f,  0.96592582628906829f,
    0.86602540378443865f,  0.70710678118654752f,  0.5f,  0.25881904510252076f,
    0.0f, -0.25881904510252076f, -0.5f,                 -0.70710678118654752f,
   -0.86602540378443865f, -0.96592582628906829f, -1.0f, -0.96592582628906829f,
   -0.86602540378443865f, -0.70710678118654752f, -0.5f, -0.25881904510252076f
};

// ---------------- volume padding: zero borders, copy interior ----------------
__global__ __launch_bounds__(256) void pad_kernel(const float* __restrict__ vol,
                                                  float* __restrict__ padv) {
    int i = blockIdx.x * 256 + threadIdx.x;
    if (i >= PVN) return;
    int x = i % PPX;
    int t = i / PPX;
    int y = t % PPY;
    int z = t / PPY;
    float val = 0.0f;
    if (z >= 2 && z <= 65 && y >= 1 && y <= 128 && x >= 1 && x <= 128)
        val = vol[(((z - 2) << 7) + (y - 1) << 7) + (x - 1)];
    padv[i] = val;
}

// Per-ray geometry for FP.
__device__ __forceinline__ void ray_setup(int a, int v, int u,
                                          float& sx, float& sy,
                                          float& dx, float& dy, float& dz) {
    float ang = (float)((double)a * (15.0 * M_PI / 180.0));
    float c = cosf(ang), s = sinf(ang);
    float uu = (float)u - 63.5f;
    float vv = (float)v - 31.5f;
    float ux = 512.0f * c - uu * s;
    float uy = 512.0f * s + uu * c;
    float uz = vv;
    float invn = 1.0f / sqrtf(ux * ux + uy * uy + uz * uz);
    dx = ux * invn; dy = uy * invn; dz = uz * invn;
    sx = -256.0f * c; sy = -256.0f * s;
}

// ---------------- forward projection, 4 ell-segments, padded-volume gather ----------------
__global__ __launch_bounds__(256) void fp_seg_kernel(const float* __restrict__ padv,
                                                     float* __restrict__ part) {
    int r = blockIdx.x * blockDim.x + threadIdx.x;
    int seg = blockIdx.y;
    int u = r & (NU - 1);
    int v = (r >> 7) & (NV - 1);
    int a = r >> 13;

    float sx, sy, dx, dy, dz;
    ray_setup(a, v, u, sx, sy, dx, dy, dz);

    // exact-support window (voxel weights are zero outside +-64.5 / +-32.5)
    float rx = 1.0f / dx, ry = 1.0f / dy, rz = 1.0f / dz;
    float ex0 = (-64.51f - sx) * rx, ex1 = (64.51f - sx) * rx;
    float ey0 = (-64.51f - sy) * ry, ey1 = (64.51f - sy) * ry;
    float ez0 = (-32.51f) * rz,      ez1 = (32.51f) * rz;
    float llo = fmaxf(fmaxf(fminf(ex0, ex1), fminf(ey0, ey1)), fminf(ez0, ez1));
    float lhi = fminf(fminf(fmaxf(ex0, ex1), fmaxf(ey0, ey1)), fmaxf(ez0, ez1));
    int i_lo = max(seg * 32,      (int)ceilf((llo - F_L0) * INV_DL));
    int i_hi = min(seg * 32 + 31, (int)floorf((lhi - F_L0) * INV_DL));

    float acc = 0.0f;
    for (int i = i_lo; i <= i_hi; ++i) {
        float ell = fmaf((float)i, F_DL, F_L0);
        float cx = fmaf(ell, dx, sx) + 63.5f;   // voxel-index space
        float cy = fmaf(ell, dy, sy) + 63.5f;
        float cz = ell * dz + 31.5f;
        float fx = floorf(cx), fy = floorf(cy), fz = floorf(cz);
        int ix = (int)fx, iy = (int)fy, iz = (int)fz;
        float wx1 = cx - fx, wy1 = cy - fy, wz1 = cz - fz;
        int base = iz * PPLANE + iy * PPX + ix + CBASE;
        const float* q0 = padv + base;
        const float* q1 = q0 + PPLANE;
        float v000 = q0[0],   v001 = q0[1];
        float v010 = q0[PPX], v011 = q0[PPX + 1];
        float v100 = q1[0],   v101 = q1[1];
        float v110 = q1[PPX], v111 = q1[PPX + 1];
        float c00 = fmaf(wx1, v001 - v000, v000);
        float c01 = fmaf(wx1, v011 - v010, v010);
        float c10 = fmaf(wx1, v101 - v100, v100);
        float c11 = fmaf(wx1, v111 - v110, v110);
        float c0  = fmaf(wy1, c01 - c00, c00);
        float c1  = fmaf(wy1, c11 - c10, c10);
        acc += fmaf(wz1, c1 - c0, c0);
    }
    part[seg * NRAYS + r] = acc;
}

// ------- residual + cw + Ram-Lak; writes TRANSPOSED resT[a][u][v] -------
__global__ __launch_bounds__(NU) void ramp_kernel(const float* __restrict__ part,
                                                  const float* __restrict__ p,
                                                  float* __restrict__ resT) {
    __shared__ float row[NU];
    int rowid = blockIdx.x;          // a*NV + v
    int u = threadIdx.x;
    int e = rowid * NU + u;
    int a = rowid >> 6;
    int v = rowid & (NV - 1);
    float sino = (part[e] + part[NRAYS + e] + part[2 * NRAYS + e] + part[3 * NRAYS + e]) * F_STEP;
    double du = (double)u - 64.0;
    double dv = (double)v - 32.0;
    float cw = (float)(512.0 / sqrt(262144.0 + dv * dv + du * du));
    row[u] = (sino - p[e]) * cw;
    __syncthreads();
    float acc = 0.125f * row[u];
#pragma unroll
    for (int d = 1; d <= 63; d += 2) {
        float f = (float)(-0.5 / (M_PI * M_PI * (double)(d * d)));
        float lo = (u - d >= 0) ? row[u - d] : 0.0f;
        float hi = (u + d < NU) ? row[u + d] : 0.0f;
        acc += f * (lo + hi);
    }
    resT[(a << 13) + (u << 6) + v] = acc;   // [a][u][v]
}

// ---------------- back projection: LDS-staged columns, VMEM-free k-loop ----------------
// R20. Attribution so far (R0-R4): VALU issue = 151us/SIMD (45% of 335us);
// each wave is ~94% stalled; NOT setup latency, NOT occupancy, NOT phase
// correlation, NOT bank conflicts, NOT HBM. Remaining suspect: the k-loop's
// register prefetch does not survive compilation -- the compiler can sink the
// Cr/Dr global loads below the bodies (minimizing pressure at 32 VGPR) and
// emit s_waitcnt vmcnt(0) right after, exposing full L2/L3 latency EVERY
// k-iteration (~48 iters x ~2-4K cy = the missing ~100+ us/wave). This is the
// documented HIP failure mode: source-level vmcnt discipline is not preserved.
// R20 removes VMEM from the k-loop entirely:
//  * per pair, stage trips columns x 2 angles into WAVE-PRIVATE LDS via
//    global_load_lds (64 lanes x 4B = one 256B column per instr; linear
//    wave-uniform dest + lane*4 -- the required discipline);
//  * one explicit s_waitcnt vmcnt(0) per PAIR (~400cy x 12 = ~2us/wave);
//  * k-loop reads via ds_read (~120cy, hidden by 4 independent bodies;
//    compiler emits fine-grained lgkmcnt for ds_read->use).
// trips <= 12 PROVEN: u-window width = 1024*ab*(R+eta)/(R^2-ab^2) with
// R=256+xi, xi^2+eta^2 <= 2*63.5^2, ab<=sqrt2 -> max 10.2 -> len <= 11.
// LDS: 4 waves x 2 angles x 12 cols x 256B + s_acc = 25600 B/block ->
// 6 blocks/CU (24 waves, ~= the 22.7 achieved now). launch_bounds(256,6)
// caps VGPR at ~42 (body needs ~30, no spill). Staged values are bit-
// identical to what the register pipeline read -> identical arithmetic.

#define SETUP_ANGLE(S, AIDX, AB)                                                 \
    const float c##S = CSA[AIDX], sn##S = SNA[AIDX];                             \
    const float c512##S = 512.0f * c##S;                                         \
    const float s512##S = 512.0f * sn##S;                                        \
    const float rho##S = fmaf(x0, c##S, fmaf(y0, sn##S, 256.0f));                \
    const float Vx##S = x0 + 256.0f * c##S;                                      \
    const float Vy##S = y0 + 256.0f * sn##S;                                     \
    const float tvlo##S = (rho##S - (AB)) * (1.0f / 512.0f);                     \
    const float yp##S = y0 * c##S - x0 * sn##S;                                  \
    const float rl##S = __builtin_amdgcn_rcpf(rho##S - (AB));                    \
    const float rh##S = __builtin_amdgcn_rcpf(rho##S + (AB));                    \
    const float A##S = yp##S - (AB), B##S = yp##S + (AB);                        \
    const float um##S = 512.0f * A##S * ((A##S >= 0.0f) ? rh##S : rl##S);        \
    const float uM##S = 512.0f * B##S * ((B##S >= 0.0f) ? rl##S : rh##S);        \
    const int u_lo##S = max(0,   (int)ceilf(um##S + 63.49f));                    \
    const int u_hi##S = min(127, (int)floorf(uM##S + 63.51f));                   \
    const int len##S = max(0, u_hi##S - u_lo##S + 1);                            \
    const float Zmin##S = fmaf(vvf, (vvf >= 0.0f) ? (tvlo##S - 1.0e-3f)          \
                                                  : (tvlo##S + 7.2e-3f), 31.5f); \
    const float izbf##S = floorf(Zmin##S);                                       \
    const int   izb##S  = (int)izbf##S;                                          \
    const v2f b0##S = {izbf##S, izbf##S};                                        \
    const float tDL##S = tvlo##S * INV_DL;                                       \
    const v2f mVx##S = {-Vx##S, -Vx##S}, mVy##S = {-Vy##S, -Vy##S};

#define BP_BODY2(S, RV, UU) do {                                                 \
    const float pu = fmaf(-(UU), sn##S, c512##S);                                \
    const float qu = fmaf((UU), c##S, s512##S);                                  \
    const float arg  = fmaf((UU), (UU), s2);                                     \
    const float invn = __builtin_amdgcn_rsqf(arg);                               \
    const float nn   = arg * invn;                                               \
    const float i0f  = ceilf(fmaf(tDL##S, nn, cK));                              \
    const float ell0 = fmaf(i0f, F_DL, F_L0);                                    \
    v2f tp; tp.x = ell0 * invn; tp.y = fmaf(F_DL, invn, tp.x);                   \
    const v2f pu2 = {pu, pu}, qu2 = {qu, qu};                                    \
    v2f wx = __builtin_elementwise_max(                                          \
        one2 - __builtin_elementwise_abs(__builtin_elementwise_fma(tp, pu2, mVx##S)), zero2); \
    v2f wy = __builtin_elementwise_max(                                          \
        one2 - __builtin_elementwise_abs(__builtin_elementwise_fma(tp, qu2, mVy##S)), zero2); \
    v2f val = wx * wy * (v2f){(RV), (RV)};                                       \
    const v2f fz2 = __builtin_elementwise_fma(tp, vv2, h31);                     \
    const v2f g  = fz2 - b0##S;                                                  \
    const v2f h1 = g - one2;                                                     \
    AC0##S = __builtin_elementwise_fma(__builtin_elementwise_max(                \
             one2 - __builtin_elementwise_abs(g), zero2), val, AC0##S);          \
    AC1##S = __builtin_elementwise_fma(__builtin_elementwise_max(                \
             one2 - __builtin_elementwise_abs(h1), zero2), val, AC1##S);         \
    AC2##S = __builtin_elementwise_fma(__builtin_elementwise_max(h1, zero2), val, AC2##S); \
} while (0)

#define MAXCOLS 12

__global__ __launch_bounds__(256, 6) void bp_gather19(const float* __restrict__ resT,
                                                      float* __restrict__ out) {
    __shared__ float s_res[4][2][MAXCOLS][64];   // wave-private staged columns
    __shared__ float s_acc[4 * 64];              // per-wave z-accumulator columns

    const int tid  = threadIdx.x;
    const int lane = tid & 63;            // = v
    const int wv   = tid >> 6;            // wave 0..3
    const int y    = blockIdx.x & 127;    // y-major
    const int xq   = blockIdx.x >> 7;     // 0..31
    const int xi   = xq * 4 + wv;         // 4 consecutive x per block

    const float x0 = (float)xi - 63.5f;
    const float y0 = (float)y  - 63.5f;
    const float vvf = (float)lane - 31.5f;
    const float s2  = fmaf(vvf, vvf, 262144.0f);   // vv^2 + 512^2
    const v2f vv2   = {vvf, vvf};
    const v2f one2  = {1.0f, 1.0f}, zero2 = {0.0f, 0.0f};
    const v2f h31   = {31.5f, 31.5f};
    const float cK  = -(F_L0 * INV_DL) - 1.0e-3f;

    s_acc[tid] = 0.0f;

    // per-wave rotated pair order (kept from R4: free, decorrelates staging bursts)
    int pj = __builtin_amdgcn_readfirstlane(3 * (tid >> 6));

    for (int j = 0; j < NA / 2; ++j) {
        const int a0 = __builtin_amdgcn_readfirstlane(2 * pj);
        const int a1 = a0 + 1;
        const float ab1a = fabsf(CSA[a0]) + fabsf(SNA[a0]);
        const float ab1b = fabsf(CSA[a1]) + fabsf(SNA[a1]);

        SETUP_ANGLE(0, a0, ab1a);         // adjacent pair: lengths nearly equal
        SETUP_ANGLE(1, a1, ab1b);

        const int trips = (max(len0, len1) + 1) & ~1;   // even; <= 12 (proven)
        pj = (pj + 1 == NA / 2) ? 0 : pj + 1;
        if (trips == 0) continue;
        const int us0 = max(0, min(u_lo0, 128 - trips));
        const int us1 = max(0, min(u_lo1, 128 - trips));

        // ---- stage trips columns x 2 angles into wave-private LDS ----
        const float* g0 = resT + (a0 << 13) + (us0 << 6) + lane;
        const float* g1 = resT + (a1 << 13) + (us1 << 6) + lane;
        for (int t = 0; t < trips; ++t) {
            __builtin_amdgcn_global_load_lds(
                (const AS1 unsigned int*)(g0 + (t << 6)),
                (AS3 unsigned int*)&s_res[wv][0][t][0], 4, 0, 0);
            __builtin_amdgcn_global_load_lds(
                (const AS1 unsigned int*)(g1 + (t << 6)),
                (AS3 unsigned int*)&s_res[wv][1][t][0], 4, 0, 0);
        }
        asm volatile("s_waitcnt vmcnt(0)" ::: "memory");   // once per PAIR

        v2f AC00 = zero2, AC10 = zero2, AC20 = zero2;
        v2f AC01 = zero2, AC11 = zero2, AC21 = zero2;

        float uu0 = (float)us0 - 63.5f;
        float uu1 = (float)us1 - 63.5f;

#pragma unroll 1
        for (int k = 0; k < trips; k += 2) {
            const float Ar0 = s_res[wv][0][k][lane];
            const float Ar1 = s_res[wv][1][k][lane];
            const float Br0 = s_res[wv][0][k + 1][lane];
            const float Br1 = s_res[wv][1][k + 1][lane];
            BP_BODY2(0, Ar0, uu0);
            BP_BODY2(1, Ar1, uu1);
            BP_BODY2(0, Br0, uu0 + 1.0f);
            BP_BODY2(1, Br1, uu1 + 1.0f);
            uu0 += 2.0f;
            uu1 += 2.0f;
        }

        float* accw = s_acc + (wv << 6);      // wave-private column
        atomicAdd(&accw[izb0],     AC00.x + AC00.y);
        atomicAdd(&accw[izb0 + 1], AC10.x + AC10.y);
        atomicAdd(&accw[izb0 + 2], AC20.x + AC20.y);
        atomicAdd(&accw[izb1],     AC01.x + AC01.y);
        atomicAdd(&accw[izb1 + 1], AC11.x + AC11.y);
        atomicAdd(&accw[izb1 + 2], AC21.x + AC21.y);
    }
    __syncthreads();

    // writeout: 4 consecutive x per 4 lanes -> 16B chunks
    const int z  = tid >> 2;
    const int w4 = tid & 3;
    out[(z << 14) + (y << 7) + xq * 4 + w4] = s_acc[(w4 << 6) + z] * F_STEP;
}

extern "C" void kernel_launch(void* const* d_in, const int* in_sizes, int n_in,
                              void* d_out, int out_size, void* d_ws, size_t ws_size,
                              hipStream_t stream) {
    const float* x = (const float*)d_in[0];   // [1,1,64,128,128]
    const float* p = (const float*)d_in[1];   // [1,1,24,64,128]
    float* out  = (float*)d_out;              // [1,1,64,128,128]
    float* resT = (float*)d_ws;               // transposed filtered residual, NRAYS floats
    float* part = resT + NRAYS;               // 4 FP segments, 4*NRAYS floats
    float* padv = part + NSEG * NRAYS;        // padded volume, PVN floats (~4.6 MB)

    pad_kernel<<<(PVN + 255) / 256, 256, 0, stream>>>(x, padv);
    dim3 fpg(NRAYS / 256, NSEG);
    fp_seg_kernel<<<fpg, 256, 0, stream>>>(padv, part);
    ramp_kernel<<<NA * NV, NU, 0, stream>>>(part, p, resT);
    bp_gather19<<<128 * 32, 256, 0, stream>>>(resT, out);
}